// Round 5
// baseline (1306.701 us; speedup 1.0000x reference)
//
#include <hip/hip_runtime.h>
#include <hip/hip_bf16.h>
#include <math.h>

#define NT 1024
#define BSZ 128
#define TSTEPS 32
#define DIN 128
#define DHH 128
#define NSLOT 512
#define EPSF 1e-8f

// LDS layout (bytes):
//   [0, 131072)        memL  bf16[512*128]  persistent NTM memory state
//   [131072, 155744)   F     float[6168]    scratch
static constexpr size_t LDS_BYTES = 131072 + 6168 * sizeof(float);

__device__ __forceinline__ float us2f(unsigned short u) {
  union { unsigned short s; __hip_bfloat16 h; } c; c.s = u; return __bfloat162float(c.h);
}
__device__ __forceinline__ unsigned short f2us(float f) {
  union { unsigned short s; __hip_bfloat16 h; } c; c.h = __float2bfloat16(f); return c.s;
}
__device__ __forceinline__ float sigmoid_(float x) { return 1.0f / (1.0f + __expf(-x)); }
__device__ __forceinline__ float softplus_(float x) {
  return fmaxf(x, 0.0f) + log1pf(__expf(-fabsf(x)));
}
__device__ __forceinline__ float tanh_(float x) {
  float e = __expf(-2.0f * fabsf(x));
  float t = (1.0f - e) / (1.0f + e);
  return copysignf(t, x);
}
__device__ __forceinline__ float waveSum(float v) {
#pragma unroll
  for (int m = 32; m >= 1; m >>= 1) v += __shfl_xor(v, m);
  return v;
}
__device__ __forceinline__ float waveMax(float v) {
#pragma unroll
  for (int m = 32; m >= 1; m >>= 1) v = fmaxf(v, __shfl_xor(v, m));
  return v;
}

// NTM attention head, 1024 threads, slot = tid (threads >=512 passive but in
// all barriers / wave reductions with neutral values).
// sQ: [0..15] max partials, [16..31] expsum, [32..47] powsum.
__device__ __forceinline__ void attention_phase(
    int tid, const float* __restrict__ dot, const float* __restrict__ nrm,
    float beta, float g, float s0, float s1, float s2, float gam, float kn,
    const float* __restrict__ wprev, float* __restrict__ wg,
    float* __restrict__ wout_, float* __restrict__ sQ)
{
  const int lane = tid & 63, wid = tid >> 6;
  float sc = -1e30f;
  if (tid < NSLOT) sc = beta * dot[tid] / (nrm[tid] * kn + EPSF);
  float mx = waveMax(sc);
  if (lane == 0) sQ[wid] = mx;
  __syncthreads();
  float M = sQ[0];
#pragma unroll
  for (int q = 1; q < 16; ++q) M = fmaxf(M, sQ[q]);
  float e = (tid < NSLOT) ? __expf(sc - M) : 0.0f;
  float S = waveSum(e);
  if (lane == 0) sQ[16 + wid] = S;
  __syncthreads();
  float Ss = 0.0f;
#pragma unroll
  for (int q = 0; q < 16; ++q) Ss += sQ[16 + q];
  const float inv = 1.0f / Ss;
  if (tid < NSLOT) wg[tid] = g * (e * inv) + (1.0f - g) * wprev[tid];
  __syncthreads();
  float p = 0.0f;
  if (tid < NSLOT) {
    const float wt = s0 * wg[(tid + 1) & 511] + s1 * wg[tid] + s2 * wg[(tid - 1) & 511];
    p = powf(fmaxf(wt, 0.0f), gam);
  }
  float P = waveSum(p);
  if (lane == 0) sQ[32 + wid] = P;
  __syncthreads();
  float Ps = 0.0f;
#pragma unroll
  for (int q = 0; q < 16; ++q) Ps += sQ[32 + q];
  const float pinv = 1.0f / (Ps + EPSF);
  if (tid < NSLOT) wout_[tid] = p * pinv;
  __syncthreads();
}

// One block (1024 threads, 16 waves) per batch element; runs all 32 steps.
// mem state lives entirely in LDS (bf16); weights stream from global/L2.
__global__ __launch_bounds__(NT, 4)
void ntm_kernel(const float* __restrict__ x,
                const float* __restrict__ Wxh,
                const float* __restrict__ Whh,
                const float* __restrict__ Wrh,
                const float* __restrict__ bh,
                const float* __restrict__ Wout,
                const float* __restrict__ bout,
                const float* __restrict__ Wr,
                const float* __restrict__ br,
                const float* __restrict__ Ww,
                const float* __restrict__ bw,
                float* __restrict__ out)
{
  extern __shared__ char smem[];
  uint4* memv = (uint4*)smem;              // bf16 mem, row n = 16 uint4
  float* F = (float*)(smem + 131072);

  const int b = blockIdx.x;
  const int tid = threadIdx.x;
  const int g = tid >> 4, l = tid & 15;    // 64 groups x 16 lanes (mem sweeps)
  const int lane = tid & 63, wid = tid >> 6;

  float* sWprev = F + 0;      // 512  w_prev / becomes w_w
  float* sWr    = F + 512;    // 512  w_r
  float* sWg    = F + 1024;   // 512  attention scratch
  float* sDotR  = F + 1536;   // 512
  float* sDotW  = F + 2048;   // 512
  float* sNrm   = F + 2560;   // 512
  float* sRed   = F + 3072;   // 2048 reduction scratch
  float* sOr    = F + 5120;   // 144  (134 used)
  float* sOw    = F + 5264;   // 392  (390 used)
  float* sH     = F + 5656;   // 128
  float* sR     = F + 5784;   // 128
  float* sXt    = F + 5912;   // 128
  float* sP     = F + 6040;   // 128: [0..15] knorm, [16..63] attn1, [64..111] attn2

  // ---- state init ----
  {
    const unsigned short mb = f2us(1e-6f);
    const unsigned w32 = ((unsigned)mb << 16) | mb;
    const uint4 fv = make_uint4(w32, w32, w32, w32);
    for (int i = tid; i < NSLOT * DHH / 8; i += NT) memv[i] = fv;
  }
  for (int i = tid; i < NSLOT; i += NT) sWprev[i] = 1.0f / NSLOT;
  if (tid < DHH) { sH[tid] = 0.0f; sR[tid] = 0.0f; }
  __syncthreads();

  for (int t = 0; t < TSTEPS; ++t) {
    if (tid < DIN) sXt[tid] = x[((size_t)b * TSTEPS + t) * DIN + tid];
    __syncthreads();

    // ---- Phase H: h = tanh([x;h;r] @ [Wxh;Whh;Wrh] + bh) ----
    {
      const int j = tid & 127, s = tid >> 7;
      const int i0 = s * 48;
      float acc = 0.0f;
#pragma unroll 4
      for (int q = 0; q < 48; ++q) {
        const int i = i0 + q;
        float v; const float* Wp;
        if (i < 128)      { v = sXt[i];       Wp = Wxh + i * DHH; }
        else if (i < 256) { v = sH[i - 128];  Wp = Whh + (i - 128) * DHH; }
        else              { v = sR[i - 256];  Wp = Wrh + (i - 256) * DHH; }
        acc += v * Wp[j];
      }
      sRed[tid] = acc;
      __syncthreads();
      if (tid < DHH) {
        float a2 = bh[tid];
#pragma unroll
        for (int q = 0; q < 8; ++q) a2 += sRed[tid + 128 * q];
        sH[tid] = tanh_(a2);
      }
      __syncthreads();
    }

    // ---- Phase O: o_r = h@Wr+br (134), o_w = h@Ww+bw (390), f32 from L2 ----
    // 1048 partial-slots: slot<524 -> col c rows 0..63; else col c rows 64..127
    {
#pragma unroll
      for (int k = 0; k < 2; ++k) {
        const int slot = tid + k * NT;
        if (slot < 1048) {
          const int c  = (slot < 524) ? slot : slot - 524;
          const int r0 = (slot < 524) ? 0 : 64;
          float acc = 0.0f;
          if (c < 134) {
#pragma unroll 8
            for (int i = r0; i < r0 + 64; ++i) acc += sH[i] * Wr[i * 134 + c];
          } else {
            const int cw = c - 134;
#pragma unroll 8
            for (int i = r0; i < r0 + 64; ++i) acc += sH[i] * Ww[i * 390 + cw];
          }
          sRed[slot] = acc;
        }
      }
      __syncthreads();
      if (tid < 524) {
        const float v = sRed[tid] + sRed[524 + tid];
        if (tid < 134) sOr[tid] = v + br[tid];
        else           sOw[tid - 134] = v + bw[tid - 134];
      }
      __syncthreads();
      // k-norm partials (waves 0,1: |k_r|^2; waves 2,3: |k_w|^2) + e/a transforms
      {
        float v = 0.0f;
        if (tid < 128)      v = sOr[tid] * sOr[tid];
        else if (tid < 256) { const float z = sOw[tid - 128]; v = z * z; }
        v = waveSum(v);
        if (lane == 0) sP[wid] = v;
      }
      if (tid >= 256 && tid < 384)      { const int q = tid - 256; sOw[134 + q] = sigmoid_(sOw[134 + q]); }
      else if (tid >= 384 && tid < 512) { const int q = tid - 384; sOw[262 + q] = tanh_(sOw[262 + q]); }
      __syncthreads();
    }
    const float kn_r = sqrtf(sP[0] + sP[1]);
    const float kn_w = sqrtf(sP[2] + sP[3]);
    float beta_r, g_r, sr0, sr1, sr2, gam_r;
    float beta_w, g_w, sw0, sw1, sw2, gam_w;
    {
      beta_r = softplus_(sOr[128]); g_r = sigmoid_(sOr[129]);
      float a0 = sOr[130], a1 = sOr[131], a2 = sOr[132];
      float mx = fmaxf(a0, fmaxf(a1, a2));
      float e0 = __expf(a0 - mx), e1 = __expf(a1 - mx), e2 = __expf(a2 - mx);
      float es = e0 + e1 + e2;
      sr0 = e0 / es; sr1 = e1 / es; sr2 = e2 / es;
      gam_r = 1.0f + softplus_(sOr[133]);

      beta_w = softplus_(sOw[128]); g_w = sigmoid_(sOw[129]);
      float b0 = sOw[130], b1 = sOw[131], b2 = sOw[132];
      float mw = fmaxf(b0, fmaxf(b1, b2));
      float f0 = __expf(b0 - mw), f1 = __expf(b1 - mw), f2 = __expf(b2 - mw);
      float fs = f0 + f1 + f2;
      sw0 = f0 / fs; sw1 = f1 / fs; sw2 = f2 / fs;
      gam_w = 1.0f + softplus_(sOw[133]);
    }

    // ---- Phase A: dot_r[n], dot_w[n], ||mem_n|| — 64 groups, 8 slots each ----
    {
      float krv[8], kwv[8];
#pragma unroll
      for (int j = 0; j < 8; ++j) { krv[j] = sOr[l * 8 + j]; kwv[j] = sOw[l * 8 + j]; }
#pragma unroll 2
      for (int it = 0; it < 8; ++it) {
        const int n = g + 64 * it;
        union { uint4 v; unsigned short s[8]; } pk; pk.v = memv[n * 16 + l];
        float dr = 0.0f, dw = 0.0f, ss = 0.0f;
#pragma unroll
        for (int j = 0; j < 8; ++j) {
          const float m = us2f(pk.s[j]);
          dr += m * krv[j]; dw += m * kwv[j]; ss += m * m;
        }
#pragma unroll
        for (int mm = 8; mm >= 1; mm >>= 1) {
          dr += __shfl_xor(dr, mm);
          dw += __shfl_xor(dw, mm);
          ss += __shfl_xor(ss, mm);
        }
        if (l == 0) { sDotR[n] = dr; sDotW[n] = dw; sNrm[n] = sqrtf(ss); }
      }
      __syncthreads();
    }

    // ---- Attention: w_r (prev=w_prev) then w_w (prev=w_r; into sWprev) ----
    attention_phase(tid, sDotR, sNrm, beta_r, g_r, sr0, sr1, sr2, gam_r, kn_r,
                    sWprev, sWg, sWr, sP + 16);
    attention_phase(tid, sDotW, sNrm, beta_w, g_w, sw0, sw1, sw2, gam_w, kn_w,
                    sWr, sWg, sWprev, sP + 64);

    // ---- Phase B: r = w_r·mem (old) fused with mem update by w_w ----
    {
      float e8[8], a8[8], r8[8];
#pragma unroll
      for (int j = 0; j < 8; ++j) {
        e8[j] = sOw[134 + l * 8 + j];
        a8[j] = sOw[262 + l * 8 + j];
        r8[j] = 0.0f;
      }
#pragma unroll 2
      for (int it = 0; it < 8; ++it) {
        const int n = g + 64 * it;
        const float wrn = sWr[n];
        const float wwn = sWprev[n];   // holds w_w now
        union { uint4 v; unsigned short s[8]; } pk; pk.v = memv[n * 16 + l];
        float m[8];
#pragma unroll
        for (int j = 0; j < 8; ++j) m[j] = us2f(pk.s[j]);
#pragma unroll
        for (int j = 0; j < 8; ++j) {
          r8[j] = fmaf(wrn, m[j], r8[j]);
          const float d = fmaf(-e8[j], m[j], a8[j]);   // a - e*mem
          m[j] = fmaf(wwn, d, m[j]);                   // mem + w_w*(a - e*mem)
        }
#pragma unroll
        for (int j = 0; j < 8; ++j) pk.s[j] = f2us(m[j]);
        memv[n * 16 + l] = pk.v;
      }
      // reduce 4 groups within each wave (lanes l, l+16, l+32, l+48 share cols)
#pragma unroll
      for (int j = 0; j < 8; ++j) {
        r8[j] += __shfl_xor(r8[j], 16);
        r8[j] += __shfl_xor(r8[j], 32);
      }
      if (lane < 16) {
#pragma unroll
        for (int j = 0; j < 8; ++j) sRed[wid * 128 + lane * 8 + j] = r8[j];
      }
      __syncthreads();
      if (tid < DHH) {
        float acc = 0.0f;
#pragma unroll
        for (int q = 0; q < 16; ++q) acc += sRed[q * 128 + tid];
        sR[tid] = acc;
      }
      __syncthreads();
    }

    // ---- Phase Y: y = [h;r] @ Wout + bout ----
    {
      const int j = tid & 127, s = tid >> 7;
      const int r0 = s * 32;
      float acc = 0.0f;
#pragma unroll 4
      for (int q = 0; q < 32; ++q) {
        const int i = r0 + q;
        const float v = (i < 128) ? sH[i] : sR[i - 128];
        acc += v * Wout[i * DIN + j];
      }
      sRed[tid] = acc;
      __syncthreads();
      if (tid < DIN) {
        float y = bout[tid];
#pragma unroll
        for (int q = 0; q < 8; ++q) y += sRed[tid + 128 * q];
        out[((size_t)b * TSTEPS + t) * DIN + tid] = y;
      }
      __syncthreads();
    }
  }
}

extern "C" void kernel_launch(void* const* d_in, const int* in_sizes, int n_in,
                              void* d_out, int out_size, void* d_ws, size_t ws_size,
                              hipStream_t stream) {
  (void)in_sizes; (void)n_in; (void)out_size; (void)d_ws; (void)ws_size;
  hipFuncSetAttribute(reinterpret_cast<const void*>(ntm_kernel),
                      hipFuncAttributeMaxDynamicSharedMemorySize, (int)LDS_BYTES);
  ntm_kernel<<<dim3(BSZ), dim3(NT), LDS_BYTES, stream>>>(
      (const float*)d_in[0], (const float*)d_in[1], (const float*)d_in[2],
      (const float*)d_in[3], (const float*)d_in[4], (const float*)d_in[5],
      (const float*)d_in[6], (const float*)d_in[7], (const float*)d_in[8],
      (const float*)d_in[9], (const float*)d_in[10],
      (float*)d_out);
}

// Round 6
// 1069.192 us; speedup vs baseline: 1.2221x; 1.2221x over previous
//
#include <hip/hip_runtime.h>
#include <hip/hip_bf16.h>
#include <math.h>

#define NT 1024
#define BSZ 128
#define TSTEPS 32
#define DIN 128
#define DHH 128
#define NSLOT 512
#define EPSF 1e-8f

// LDS: [0,131072) mem bf16[512][128] XOR-swizzled; then float scratch F[6232]
static constexpr int F_FLOATS = 6232;
static constexpr size_t LDS_BYTES = 131072 + F_FLOATS * sizeof(float);

__device__ __forceinline__ float us2f(unsigned short u) {
  union { unsigned short s; __hip_bfloat16 h; } c; c.s = u; return __bfloat162float(c.h);
}
__device__ __forceinline__ unsigned short f2us(float f) {
  union { unsigned short s; __hip_bfloat16 h; } c; c.h = __float2bfloat16(f); return c.s;
}
__device__ __forceinline__ float sigmoid_(float x) { return 1.0f / (1.0f + __expf(-x)); }
__device__ __forceinline__ float softplus_(float x) {
  return fmaxf(x, 0.0f) + log1pf(__expf(-fabsf(x)));
}
__device__ __forceinline__ float tanh_(float x) {
  float e = __expf(-2.0f * fabsf(x));
  float t = (1.0f - e) / (1.0f + e);
  return copysignf(t, x);
}
__device__ __forceinline__ float waveSum(float v) {
#pragma unroll
  for (int m = 32; m >= 1; m >>= 1) v += __shfl_xor(v, m);
  return v;
}

// One block (1024 threads) per batch element; all 32 steps in-block.
// mem state in LDS, rows XOR-swizzled: stored uint4 slot u = c ^ ((n>>2)&3).
__global__ __launch_bounds__(NT, 4)
void ntm_kernel(const float* __restrict__ x,
                const float* __restrict__ Wxh,
                const float* __restrict__ Whh,
                const float* __restrict__ Wrh,
                const float* __restrict__ bh,
                const float* __restrict__ Wout,
                const float* __restrict__ bout,
                const float* __restrict__ Wr,
                const float* __restrict__ br,
                const float* __restrict__ Ww,
                const float* __restrict__ bw,
                float* __restrict__ out)
{
  extern __shared__ char smem[];
  uint4* memv = (uint4*)smem;              // bf16 mem, row n = 16 uint4 (swizzled)
  float* F = (float*)(smem + 131072);

  const int b = blockIdx.x;
  const int tid = threadIdx.x;
  const int g = tid >> 4, l = tid & 15;    // Phase-B mapping
  const int lane = tid & 63, wid = tid >> 6;

  float* sWprev = F + 0;      // 512  w_prev / becomes w_w
  float* sWr    = F + 512;    // 512  w_r
  float* sWg    = F + 1024;   // 512  attention scratch
  float* sDotR  = F + 1536;   // 512
  float* sDotW  = F + 2048;   // 512
  float* sNrm   = F + 2560;   // 512
  float* sYp    = F + 1024;   // 2048 Y-partials (reuses sWg..sNrm, dead by Phase Y)
  float* sRed   = F + 3072;   // 2048 reduction scratch (H, O, B)
  float* sOr    = F + 5120;   // 144  (134 used)
  float* sOw    = F + 5264;   // 392  (390 used)
  float* sH     = F + 5656;   // 128
  float* sR     = F + 5784;   // 128
  float* sXt    = F + 5912;   // 128
  float* sP     = F + 6040;   // 64: [0..15] knorm, [16..31] esumR, [32..47] esumW, [48..63] psum
  uint4* krP    = (uint4*)(F + 6104);   // 16 uint4: k_r packed bf16
  uint4* kwP    = (uint4*)(F + 6168);   // 16 uint4: k_w packed bf16

  // ---- init ----
  {
    const unsigned short mb = f2us(1e-6f);
    const unsigned w32 = ((unsigned)mb << 16) | mb;
    const uint4 fv = make_uint4(w32, w32, w32, w32);
    for (int i = tid; i < NSLOT * DHH / 8; i += NT) memv[i] = fv;
  }
  for (int i = tid; i < NSLOT; i += NT) sWprev[i] = 1.0f / NSLOT;
  if (tid < DHH) { sH[tid] = 0.0f; sR[tid] = 0.0f; }
  if (tid < DIN) sXt[tid] = x[(size_t)b * TSTEPS * DIN + tid];
  __syncthreads();

  for (int t = 0; t < TSTEPS; ++t) {
    // ---- Phase H partials (+ y-finalize of previous step, disjoint buffers) ----
    {
      if (t > 0 && tid < DIN) {
        float y = bout[tid];
#pragma unroll
        for (int q = 0; q < 8; ++q) y += sYp[tid + 128 * q];
        out[((size_t)b * TSTEPS + (t - 1)) * DIN + tid] = y;
      }
      const int j = tid & 127, s = tid >> 7;
      const int i0 = s * 48;
      float acc = 0.0f;
#pragma unroll 4
      for (int q = 0; q < 48; ++q) {
        const int i = i0 + q;
        float v; const float* Wp;
        if (i < 128)      { v = sXt[i];       Wp = Wxh + i * DHH; }
        else if (i < 256) { v = sH[i - 128];  Wp = Whh + (i - 128) * DHH; }
        else              { v = sR[i - 256];  Wp = Wrh + (i - 256) * DHH; }
        acc += v * Wp[j];
      }
      sRed[tid] = acc;
      __syncthreads();
      if (tid < DHH) {
        float a2 = bh[tid];
#pragma unroll
        for (int q = 0; q < 8; ++q) a2 += sRed[tid + 128 * q];
        sH[tid] = tanh_(a2);
      }
      __syncthreads();
    }

    // ---- Phase O: o_r (134), o_w (390) from global f32 (L2-resident) ----
    {
#pragma unroll
      for (int k = 0; k < 2; ++k) {
        const int slot = tid + k * NT;
        if (slot < 1048) {
          const int c  = (slot < 524) ? slot : slot - 524;
          const int r0 = (slot < 524) ? 0 : 64;
          float acc = 0.0f;
          if (c < 134) {
#pragma unroll 8
            for (int i = r0; i < r0 + 64; ++i) acc += sH[i] * Wr[i * 134 + c];
          } else {
            const int cw = c - 134;
#pragma unroll 8
            for (int i = r0; i < r0 + 64; ++i) acc += sH[i] * Ww[i * 390 + cw];
          }
          sRed[slot] = acc;
        }
      }
      __syncthreads();
      if (tid < 524) {
        const float v = sRed[tid] + sRed[524 + tid];
        if (tid < 134) sOr[tid] = v + br[tid];
        else           sOw[tid - 134] = v + bw[tid - 134];
      }
      __syncthreads();
      // knorm partials (waves 0-3) + e/a transforms (256..511) + key packing (512..543)
      {
        float v = 0.0f;
        if (tid < 128)      v = sOr[tid] * sOr[tid];
        else if (tid < 256) { const float z = sOw[tid - 128]; v = z * z; }
        v = waveSum(v);
        if (lane == 0) sP[wid] = v;
      }
      if (tid >= 256 && tid < 384)      { const int q = tid - 256; sOw[134 + q] = sigmoid_(sOw[134 + q]); }
      else if (tid >= 384 && tid < 512) { const int q = tid - 384; sOw[262 + q] = tanh_(sOw[262 + q]); }
      else if (tid >= 512 && tid < 544) {
        const int t2 = tid - 512;            // 0..31: [key][chunk]
        const int c = t2 & 15;
        const float* src = (t2 < 16) ? (sOr + c * 8) : (sOw + c * 8);
        union { uint4 v; unsigned short h[8]; } pk;
#pragma unroll
        for (int j = 0; j < 8; ++j) pk.h[j] = f2us(src[j]);
        if (t2 < 16) krP[c] = pk.v; else kwP[c] = pk.v;
      }
      __syncthreads();
    }
    // head scalars (redundant per-thread, LDS broadcast reads)
    const float kn_r = sqrtf(sP[0] + sP[1]);
    const float kn_w = sqrtf(sP[2] + sP[3]);
    float beta_r, g_r, sr0, sr1, sr2, gam_r;
    float beta_w, g_w, sw0, sw1, sw2, gam_w;
    {
      beta_r = softplus_(sOr[128]); g_r = sigmoid_(sOr[129]);
      float a0 = sOr[130], a1 = sOr[131], a2 = sOr[132];
      float mx = fmaxf(a0, fmaxf(a1, a2));
      float e0 = __expf(a0 - mx), e1 = __expf(a1 - mx), e2 = __expf(a2 - mx);
      float es = e0 + e1 + e2;
      sr0 = e0 / es; sr1 = e1 / es; sr2 = e2 / es;
      gam_r = 1.0f + softplus_(sOr[133]);

      beta_w = softplus_(sOw[128]); g_w = sigmoid_(sOw[129]);
      float b0 = sOw[130], b1 = sOw[131], b2 = sOw[132];
      float mw = fmaxf(b0, fmaxf(b1, b2));
      float f0 = __expf(b0 - mw), f1 = __expf(b1 - mw), f2 = __expf(b2 - mw);
      float fs = f0 + f1 + f2;
      sw0 = f0 / fs; sw1 = f1 / fs; sw2 = f2 / fs;
      gam_w = 1.0f + softplus_(sOw[133]);
    }

    // ---- Phase A: thread-owns-half-row, swizzled b128 reads, no shfl tree ----
    {
      const int n = tid >> 1, hf = tid & 1;
      const int sw = (n >> 2) & 3;
      float dr = 0.0f, dw = 0.0f, ss = 0.0f;
#pragma unroll
      for (int c = 0; c < 8; ++c) {
        const int cl = hf * 8 + c;
        union { uint4 v; unsigned short h[8]; } mv, kr, kw;
        mv.v = memv[n * 16 + (cl ^ sw)];
        kr.v = krP[cl];
        kw.v = kwP[cl];
#pragma unroll
        for (int j = 0; j < 8; ++j) {
          const float m = us2f(mv.h[j]);
          dr = fmaf(m, us2f(kr.h[j]), dr);
          dw = fmaf(m, us2f(kw.h[j]), dw);
          ss = fmaf(m, m, ss);
        }
      }
      dr += __shfl_xor(dr, 1);
      dw += __shfl_xor(dw, 1);
      ss += __shfl_xor(ss, 1);
      if (hf == 0) { sDotR[n] = dr; sDotW[n] = dw; sNrm[n] = sqrtf(ss); }
      __syncthreads();
    }

    // ---- Attention, both heads fused; no max-subtract (|score| <= beta, small) ----
    float e_r = 0.0f, e_w = 0.0f;
    {
      if (tid < NSLOT) {
        const float nr = sNrm[tid];
        e_r = __expf(beta_r * sDotR[tid] / (nr * kn_r + EPSF));
        e_w = __expf(beta_w * sDotW[tid] / (nr * kn_w + EPSF));
      }
      float s1 = waveSum(e_r);
      float s2 = waveSum(e_w);
      if (lane == 0) { sP[16 + wid] = s1; sP[32 + wid] = s2; }
      __syncthreads();
    }
    float invE_r, invE_w;
    {
      float SR = 0.0f, SW = 0.0f;
#pragma unroll
      for (int q = 0; q < 16; ++q) { SR += sP[16 + q]; SW += sP[32 + q]; }
      invE_r = 1.0f / SR; invE_w = 1.0f / SW;
      if (tid < NSLOT) sWg[tid] = g_r * (e_r * invE_r) + (1.0f - g_r) * sWprev[tid];
      __syncthreads();
    }
    float p1 = 0.0f;
    {
      if (tid < NSLOT) {
        const float wt = sr0 * sWg[(tid + 1) & 511] + sr1 * sWg[tid] + sr2 * sWg[(tid - 1) & 511];
        p1 = (wt > 0.0f) ? __expf(gam_r * __logf(wt)) : 0.0f;
      }
      float P = waveSum(p1);
      if (lane == 0) sP[48 + wid] = P;
      __syncthreads();
    }
    {
      float PS = 0.0f;
#pragma unroll
      for (int q = 0; q < 16; ++q) PS += sP[48 + q];
      const float pinv = 1.0f / (PS + EPSF);
      if (tid < NSLOT) {
        const float wr = p1 * pinv;
        sWr[tid] = wr;
        sWg[tid] = g_w * (e_w * invE_w) + (1.0f - g_w) * wr;
      }
      __syncthreads();
    }
    float p2 = 0.0f;
    {
      if (tid < NSLOT) {
        const float wt = sw0 * sWg[(tid + 1) & 511] + sw1 * sWg[tid] + sw2 * sWg[(tid - 1) & 511];
        p2 = (wt > 0.0f) ? __expf(gam_w * __logf(wt)) : 0.0f;
      }
      float P = waveSum(p2);
      if (lane == 0) sP[48 + wid] = P;
      __syncthreads();
    }
    {
      float PS = 0.0f;
#pragma unroll
      for (int q = 0; q < 16; ++q) PS += sP[48 + q];
      const float pinv = 1.0f / (PS + EPSF);
      if (tid < NSLOT) sWprev[tid] = p2 * pinv;   // w_w
      __syncthreads();
    }

    // ---- Phase B: r = w_r·mem (old) fused with mem update by w_w ----
    {
      const int cl = l ^ ((g >> 2) & 3);   // logical chunk held by this lane
      float e8[8], a8[8], r8[8];
#pragma unroll
      for (int j = 0; j < 8; ++j) {
        e8[j] = sOw[134 + cl * 8 + j];
        a8[j] = sOw[262 + cl * 8 + j];
        r8[j] = 0.0f;
      }
#pragma unroll 2
      for (int it = 0; it < 8; ++it) {
        const int n = g + 64 * it;
        const float wrn = sWr[n];
        const float wwn = sWprev[n];
        union { uint4 v; unsigned short s[8]; } pk; pk.v = memv[n * 16 + l];
        float m[8];
#pragma unroll
        for (int j = 0; j < 8; ++j) m[j] = us2f(pk.s[j]);
#pragma unroll
        for (int j = 0; j < 8; ++j) {
          r8[j] = fmaf(wrn, m[j], r8[j]);
          const float d = fmaf(-e8[j], m[j], a8[j]);
          m[j] = fmaf(wwn, d, m[j]);
        }
#pragma unroll
        for (int j = 0; j < 8; ++j) pk.s[j] = f2us(m[j]);
        memv[n * 16 + l] = pk.v;
      }
      // partners g^1, g^2 share (g>>2) -> same logical chunk: valid adds
#pragma unroll
      for (int j = 0; j < 8; ++j) {
        r8[j] += __shfl_xor(r8[j], 16);
        r8[j] += __shfl_xor(r8[j], 32);
      }
      if (lane < 16) {
#pragma unroll
        for (int j = 0; j < 8; ++j) sRed[wid * 128 + cl * 8 + j] = r8[j];
      }
      __syncthreads();
      if (tid < DHH) {
        float acc = 0.0f;
#pragma unroll
        for (int q = 0; q < 16; ++q) acc += sRed[q * 128 + tid];
        sR[tid] = acc;
      }
      __syncthreads();
    }

    // ---- Phase Y partials (into sYp) + x prefetch for next step ----
    {
      if (tid < DIN && t + 1 < TSTEPS)
        sXt[tid] = x[((size_t)b * TSTEPS + (t + 1)) * DIN + tid];
      const int j = tid & 127, s = tid >> 7;
      const int r0 = s * 32;
      float acc = 0.0f;
#pragma unroll 4
      for (int q = 0; q < 32; ++q) {
        const int i = r0 + q;
        const float v = (i < 128) ? sH[i] : sR[i - 128];
        acc += v * Wout[i * DIN + j];
      }
      sYp[tid] = acc;
      __syncthreads();
    }
  }

  // final y
  if (tid < DIN) {
    float y = bout[tid];
#pragma unroll
    for (int q = 0; q < 8; ++q) y += sYp[tid + 128 * q];
    out[((size_t)b * TSTEPS + (TSTEPS - 1)) * DIN + tid] = y;
  }
}

extern "C" void kernel_launch(void* const* d_in, const int* in_sizes, int n_in,
                              void* d_out, int out_size, void* d_ws, size_t ws_size,
                              hipStream_t stream) {
  (void)in_sizes; (void)n_in; (void)out_size; (void)d_ws; (void)ws_size;
  hipFuncSetAttribute(reinterpret_cast<const void*>(ntm_kernel),
                      hipFuncAttributeMaxDynamicSharedMemorySize, (int)LDS_BYTES);
  ntm_kernel<<<dim3(BSZ), dim3(NT), LDS_BYTES, stream>>>(
      (const float*)d_in[0], (const float*)d_in[1], (const float*)d_in[2],
      (const float*)d_in[3], (const float*)d_in[4], (const float*)d_in[5],
      (const float*)d_in[6], (const float*)d_in[7], (const float*)d_in[8],
      (const float*)d_in[9], (const float*)d_in[10],
      (float*)d_out);
}